// Round 1
// baseline (615.555 us; speedup 1.0000x reference)
//
#include <hip/hip_runtime.h>
#include <cfloat>
#include <cmath>

#define NB_CODE 1024
#define CODE_DIM 64
#define NROWS (32 * 8192)          // N*T = 262144
#define NTC ((size_t)NROWS * CODE_DIM)

// ws layout (as float/uint words):
//   [0 .. 1023]   counts (uint)
//   [1024]        loss_sum (float, atomic)
//   [1025 .. 2048] cnorm[1024] (float)

__global__ void cnorm_kernel(const float* __restrict__ cb, float* __restrict__ cnorm) {
    int j = blockIdx.x * blockDim.x + threadIdx.x;
    if (j >= NB_CODE) return;
    const float4* c4 = reinterpret_cast<const float4*>(cb + (size_t)j * CODE_DIM);
    float s = 0.f;
#pragma unroll
    for (int k = 0; k < CODE_DIM / 4; ++k) {
        float4 v = c4[k];
        s += v.x * v.x + v.y * v.y + v.z * v.z + v.w * v.w;
    }
    cnorm[j] = s;
}

__global__ __launch_bounds__(256) void vq_main_kernel(
    const float* __restrict__ x, const float* __restrict__ cb,
    const float* __restrict__ cnorm, float* __restrict__ out,
    unsigned int* __restrict__ counts, float* __restrict__ loss_sum)
{
    int row = blockIdx.x * blockDim.x + threadIdx.x;
    if (row >= NROWS) return;

    // Load this row of x into registers (64 f32).
    float xr[CODE_DIM];
    const float4* x4 = reinterpret_cast<const float4*>(x + (size_t)row * CODE_DIM);
#pragma unroll
    for (int k = 0; k < CODE_DIM / 4; ++k) {
        float4 v = x4[k];
        xr[4 * k + 0] = v.x; xr[4 * k + 1] = v.y;
        xr[4 * k + 2] = v.z; xr[4 * k + 3] = v.w;
    }

    // argmin_j  cnorm[j] - 2 * <x, cb_j>   (||x||^2 constant per row -> dropped)
    float best = FLT_MAX;
    int bestj = 0;
    for (int j = 0; j < NB_CODE; ++j) {
        const float* c = cb + (size_t)j * CODE_DIM;   // wave-uniform address -> s_load
        float d0 = 0.f, d1 = 0.f, d2 = 0.f, d3 = 0.f;
#pragma unroll
        for (int k = 0; k < CODE_DIM; k += 4) {
            d0 = fmaf(xr[k + 0], c[k + 0], d0);
            d1 = fmaf(xr[k + 1], c[k + 1], d1);
            d2 = fmaf(xr[k + 2], c[k + 2], d2);
            d3 = fmaf(xr[k + 3], c[k + 3], d3);
        }
        float dot = (d0 + d1) + (d2 + d3);
        float dist = fmaf(-2.f, dot, cnorm[j]);
        if (dist < best) { best = dist; bestj = j; }   // strict '<' == first-occurrence tie-break
    }

    // Dequantize: out = codebook[bestj]; accumulate commit-loss partial.
    const float4* cbest = reinterpret_cast<const float4*>(cb + (size_t)bestj * CODE_DIM);
    float4* o4 = reinterpret_cast<float4*>(out + (size_t)row * CODE_DIM);
    float lsum = 0.f;
#pragma unroll
    for (int k = 0; k < CODE_DIM / 4; ++k) {
        float4 v = cbest[k];
        o4[k] = v;
        float dx = xr[4 * k + 0] - v.x;
        float dy = xr[4 * k + 1] - v.y;
        float dz = xr[4 * k + 2] - v.z;
        float dw = xr[4 * k + 3] - v.w;
        lsum += dx * dx + dy * dy + dz * dz + dw * dw;
    }

    atomicAdd(&counts[bestj], 1u);

    // wave-level reduce of loss partials, one atomic per wave
#pragma unroll
    for (int off = 32; off > 0; off >>= 1) lsum += __shfl_down(lsum, off, 64);
    if ((threadIdx.x & 63) == 0) atomicAdd(loss_sum, lsum);
}

__global__ void finalize_kernel(const unsigned int* __restrict__ counts,
                                const float* __restrict__ loss_sum,
                                float* __restrict__ out)
{
    __shared__ float red[NB_CODE];
    int t = threadIdx.x;
    float p = (float)counts[t] / (float)NROWS;
    red[t] = p * logf(p + 1e-7f);
    __syncthreads();
    for (int s = NB_CODE / 2; s > 0; s >>= 1) {
        if (t < s) red[t] += red[t + s];
        __syncthreads();
    }
    if (t == 0) {
        out[NTC + 0] = *loss_sum / (float)NTC;   // commit_loss
        out[NTC + 1] = expf(-red[0]);            // perplexity
    }
}

extern "C" void kernel_launch(void* const* d_in, const int* in_sizes, int n_in,
                              void* d_out, int out_size, void* d_ws, size_t ws_size,
                              hipStream_t stream) {
    const float* x  = (const float*)d_in[0];
    const float* cb = (const float*)d_in[1];
    float* out = (float*)d_out;

    float* wsf = (float*)d_ws;
    unsigned int* counts = (unsigned int*)wsf;   // [0..1023]
    float* loss  = wsf + 1024;                   // [1024]
    float* cnorm = wsf + 1025;                   // [1025..2048]

    // zero counts + loss accumulator (ws is NOT re-poisoned between replays)
    hipMemsetAsync(d_ws, 0, 1025 * sizeof(float), stream);

    cnorm_kernel<<<NB_CODE / 256, 256, 0, stream>>>(cb, cnorm);
    vq_main_kernel<<<NROWS / 256, 256, 0, stream>>>(x, cb, cnorm, out, counts, loss);
    finalize_kernel<<<1, NB_CODE, 0, stream>>>(counts, loss, out);
}